// Round 3
// baseline (454.621 us; speedup 1.0000x reference)
//
#include <hip/hip_runtime.h>
#include <math.h>

typedef unsigned short u16;
typedef short s16x8 __attribute__((ext_vector_type(8)));  // 8 bf16 lanes (4 VGPRs)
typedef float f32x4 __attribute__((ext_vector_type(4)));

// B=2, S=2048, D=2048, H=16, HD=128; qkv row width = 6144
#define ATTN_SCALE 0.08838834764831845f
#define NEG_BIG -1.0e30f

__device__ __forceinline__ u16 f2bf(float f) {
  union { float f; unsigned u; } c; c.f = f;
  return (u16)((c.u + 0x7fffu + ((c.u >> 16) & 1u)) >> 16);  // RNE
}
__device__ __forceinline__ float bf2f(u16 v) {
  union { unsigned u; float f; } c; c.u = ((unsigned)v) << 16;
  return c.f;
}
__device__ __forceinline__ f32x4 mfma16(s16x8 a, s16x8 b, f32x4 c) {
  return __builtin_amdgcn_mfma_f32_16x16x32_bf16(a, b, c, 0, 0, 0);
}
// async global->LDS DMA, 16 B/lane; LDS dest = wave-uniform base + lane*16
__device__ __forceinline__ void gl_lds16(const u16* g, u16* l) {
  __builtin_amdgcn_global_load_lds(
      (const __attribute__((address_space(1))) unsigned int*)g,
      (__attribute__((address_space(3))) unsigned int*)l, 16, 0, 0);
}

// -------- fp32 -> bf16 elementwise cast (float4 vectorized) -------------
__global__ __launch_bounds__(256) void k_cast(const float* __restrict__ in,
                                              u16* __restrict__ out, int n4) {
  const int i = blockIdx.x * 256 + threadIdx.x;
  if (i >= n4) return;
  const float4 v = ((const float4*)in)[i];
  ushort4 o;
  o.x = f2bf(v.x); o.y = f2bf(v.y); o.z = f2bf(v.z); o.w = f2bf(v.w);
  ((ushort4*)out)[i] = o;
}

// -------- fp32 [R][C] -> bf16 out[C][R] transpose+cast ------------------
__global__ __launch_bounds__(256) void k_transpose_cast(const float* __restrict__ in,
                                                        u16* __restrict__ out,
                                                        int R, int C) {
  __shared__ __attribute__((aligned(16))) u16 tile[32][33];
  const int c0 = blockIdx.x * 32, r0 = blockIdx.y * 32;
  const int tx = threadIdx.x, ty = threadIdx.y;
#pragma unroll
  for (int i = 0; i < 4; ++i)
    tile[ty + 8 * i][tx] = f2bf(in[(r0 + ty + 8 * i) * C + c0 + tx]);
  __syncthreads();
#pragma unroll
  for (int i = 0; i < 4; ++i)
    out[(c0 + ty + 8 * i) * R + r0 + tx] = tile[tx][ty + 8 * i];
}

// ---------------- V -> V^T per (b,h): vt[bh][d][s] = qkv_v[b,s,h,d] ------
__global__ __launch_bounds__(256) void k_vtrans(const u16* __restrict__ qkv,
                                                u16* __restrict__ vt) {
  __shared__ __attribute__((aligned(16))) u16 tile[32][33];
  const int bh = blockIdx.z, b = bh >> 4, h = bh & 15;
  const int s0 = blockIdx.x * 32, d0 = blockIdx.y * 32;
  const int tx = threadIdx.x, ty = threadIdx.y;
#pragma unroll
  for (int i = 0; i < 4; ++i) {
    const int s = s0 + ty + 8 * i;
    tile[ty + 8 * i][tx] = qkv[(b * 2048 + s) * 6144 + 4096 + h * 128 + d0 + tx];
  }
  __syncthreads();
#pragma unroll
  for (int i = 0; i < 4; ++i) {
    const int d = d0 + ty + 8 * i;
    vt[bh * 262144 + d * 2048 + s0 + tx] = tile[tx][ty + 8 * i];
  }
}

// ---------------- RoPE in-place on Q and K sections of qkv (bf16) -------
__global__ __launch_bounds__(256) void k_rope(u16* __restrict__ qkv) {
  const int id = blockIdx.x * 256 + threadIdx.x;  // 8,388,608 threads
  const int j = id & 63;
  const int h = (id >> 6) & 15;
  const int sec = (id >> 10) & 1;
  const int m = id >> 11;  // b*2048+s
  const int s = m & 2047;
  const int base = m * 6144 + sec * 2048 + h * 128 + j;
  const float q0 = bf2f(qkv[base]);
  const float q1 = bf2f(qkv[base + 64]);
  const float inv = exp2f((float)j * -0.20762050593046014f);  // 10000^(-j/64)
  const float ang = (float)s * inv;
  float c, sn;
  sincosf(ang, &sn, &c);  // sincosf(x, SIN*, COS*) — sin FIRST
  qkv[base]      = f2bf(q0 * c - q1 * sn);
  qkv[base + 64] = f2bf(q1 * c + q0 * sn);
}

// ------- GEMM (m97 structure): C[M][N] = A[M][K] * BT[N][K]^T -----------
// kept for the fp32-A fallback path and the W_o GEMM (grid 512 blocks).
template <bool A_F32, typename OUT_T>
__global__ __launch_bounds__(256) void k_gemm_lds(const void* __restrict__ Ap, int lda,
                                                  const u16* __restrict__ BT,
                                                  OUT_T* __restrict__ C, int ldc,
                                                  int K) {
  __shared__ __attribute__((aligned(16))) u16 As[128 * 32];
  __shared__ __attribute__((aligned(16))) u16 Bs[128 * 32];
  const int tid = threadIdx.x;
  const int lane = tid & 63, wave = tid >> 6;
  const int lm = lane & 15, quad = lane >> 4;
  const int wm = wave >> 1, wn = wave & 1;
  const int m0 = blockIdx.y * 128, n0 = blockIdx.x * 128;
  const int srow = lane >> 2, scol = (lane & 3) * 8;  // staging map

  const f32x4 fzero = {0.f, 0.f, 0.f, 0.f};
  f32x4 acc[4][4];
#pragma unroll
  for (int i = 0; i < 4; ++i)
#pragma unroll
    for (int j = 0; j < 4; ++j) acc[i][j] = fzero;

  for (int k0 = 0; k0 < K; k0 += 32) {
    __syncthreads();
    if constexpr (A_F32) {
      const float* Af = (const float*)Ap;
#pragma unroll
      for (int i = 0; i < 2; ++i) {
        const int seg = tid + 256 * i;
        const int row = seg >> 2, c8 = (seg & 3) * 8;
        const float4 u = *(const float4*)&Af[(m0 + row) * lda + k0 + c8];
        const float4 w = *(const float4*)&Af[(m0 + row) * lda + k0 + c8 + 4];
        uint4 pk;
        pk.x = (unsigned)f2bf(u.x) | ((unsigned)f2bf(u.y) << 16);
        pk.y = (unsigned)f2bf(u.z) | ((unsigned)f2bf(u.w) << 16);
        pk.z = (unsigned)f2bf(w.x) | ((unsigned)f2bf(w.y) << 16);
        pk.w = (unsigned)f2bf(w.z) | ((unsigned)f2bf(w.w) << 16);
        *(uint4*)&As[row * 32 + c8] = pk;
      }
#pragma unroll
      for (int j = 0; j < 2; ++j) {
        const int rb = wave * 32 + j * 16;
        gl_lds16(&BT[(n0 + rb + srow) * K + k0 + scol], &Bs[rb * 32]);
      }
    } else {
      const u16* Ab = (const u16*)Ap;
#pragma unroll
      for (int j = 0; j < 2; ++j) {
        const int rb = wave * 32 + j * 16;
        gl_lds16(&Ab[(m0 + rb + srow) * lda + k0 + scol], &As[rb * 32]);
        gl_lds16(&BT[(n0 + rb + srow) * K + k0 + scol], &Bs[rb * 32]);
      }
    }
    __syncthreads();  // drains vmcnt (DMA) + lgkmcnt before reads

    s16x8 af[4], bfr[4];
#pragma unroll
    for (int t = 0; t < 4; ++t) {
      af[t]  = *(const s16x8*)&As[(wm * 64 + t * 16 + lm) * 32 + quad * 8];
      bfr[t] = *(const s16x8*)&Bs[(wn * 64 + t * 16 + lm) * 32 + quad * 8];
    }
#pragma unroll
    for (int mt = 0; mt < 4; ++mt)
#pragma unroll
      for (int nt = 0; nt < 4; ++nt)
        acc[mt][nt] = mfma16(af[mt], bfr[nt], acc[mt][nt]);
  }
#pragma unroll
  for (int mt = 0; mt < 4; ++mt)
#pragma unroll
    for (int nt = 0; nt < 4; ++nt)
#pragma unroll
      for (int r = 0; r < 4; ++r) {
        const float v = acc[mt][nt][r];
        const int idx = (m0 + wm * 64 + mt * 16 + quad * 4 + r) * ldc +
                        n0 + wn * 64 + nt * 16 + lm;
        if constexpr (sizeof(OUT_T) == 2) C[idx] = f2bf(v);
        else                              C[idx] = v;
      }
}

// ------- 256x256 GEMM, K-half-phase counted-vmcnt pipeline --------------
// C[M][N] = A[M][K] * BT[N][K]^T, all bf16 in, bf16 out. K=2048 fixed.
// 8 waves (2M x 4N), per-wave 128x64 output. LDS 128 KiB: 2 dbuf x 2 K-half
// x (A[256][32] + B[256][32]). Per phase (one K-half): vmcnt(4) + s_barrier,
// issue next tile's matching K-half (4 gl_lds), 12 swizzled ds_read_b128,
// setprio(1), 32 MFMA, setprio(0). Loads never drain below 4 in flight
// (T4); issue->use distance = 2 phases. Swizzle: linear LDS dest + inverse-
// swizzled global source (gc = c ^ (row&3)) + matching read (rule #21).
__global__ __launch_bounds__(512, 2) void k_gemm256(const u16* __restrict__ A,
                                                    const u16* __restrict__ BT,
                                                    u16* __restrict__ C, int ldc) {
  __shared__ __attribute__((aligned(16))) u16 As[2][2][256 * 32];
  __shared__ __attribute__((aligned(16))) u16 Bs[2][2][256 * 32];
  const int K = 2048;
  const int tid = threadIdx.x;
  const int lane = tid & 63, wave = tid >> 6;
  const int lm = lane & 15, quad = lane >> 4;
  const int wm = wave >> 2, wn = wave & 3;  // 2M x 4N wave grid

  // XCD-aware swizzle (grid=384, 384%8==0 -> simple form is bijective).
  // Column-major tile map: consecutive swizzled ids share the B panel.
  int bid = (blockIdx.x & 7) * (gridDim.x >> 3) + (blockIdx.x >> 3);
  const int m0 = (bid & 15) * 256;  // M=4096 -> 16 tiles
  const int n0 = (bid >> 4) * 256;  // N=6144 -> 24 tiles

  // stage K-half kc of K-tile kt into buffer bi (4 gl_lds per wave)
  auto stage_half = [&](int kt, int kc, int bi) {
    const int k0 = kt * 64 + kc * 32;
#pragma unroll
    for (int i = 0; i < 2; ++i) {
      const int r = i * 128 + 16 * wave + (lane >> 2);  // row within tile
      const int gc = (lane & 3) ^ (r & 3);              // inverse swizzle
      gl_lds16(&A[(m0 + r) * K + k0 + gc * 8],
               &As[bi][kc][(i * 128 + 16 * wave) * 32]);
      gl_lds16(&BT[(n0 + r) * K + k0 + gc * 8],
               &Bs[bi][kc][(i * 128 + 16 * wave) * 32]);
    }
  };

  const f32x4 fzero = {0.f, 0.f, 0.f, 0.f};
  f32x4 acc[8][4];
#pragma unroll
  for (int i = 0; i < 8; ++i)
#pragma unroll
    for (int j = 0; j < 4; ++j) acc[i][j] = fzero;

  // prologue: tile 0, both K-halves -> buf 0 (8 issues in flight)
  stage_half(0, 0, 0);
  stage_half(0, 1, 0);

  for (int t = 0; t < 32; ++t) {  // K=2048 / BK=64
    const int b = t & 1;
#pragma unroll
    for (int kc = 0; kc < 2; ++kc) {
      // phase top: counted wait (own oldest 4 = this phase's K-half landed),
      // then barrier so ALL waves' slices are visible. Never vmcnt(0) except
      // the very last phase (nothing left in flight to count against).
      if (t == 31 && kc == 1) {
        asm volatile("s_waitcnt vmcnt(0)" ::: "memory");
      } else {
        asm volatile("s_waitcnt vmcnt(4)" ::: "memory");
      }
      asm volatile("s_barrier" ::: "memory");

      // prefetch: next tile's matching K-half into the other buffer
      // (that region's last readers finished 2 barriers ago -> safe)
      if (t < 31) stage_half(t + 1, kc, b ^ 1);

      // fragment reads (swizzled): A 8, B 4 ds_read_b128
      s16x8 bfrag[4], afrag[8];
#pragma unroll
      for (int nt = 0; nt < 4; ++nt) {
        const int r = wn * 64 + nt * 16 + lm;
        const int cc = quad ^ (r & 3);
        bfrag[nt] = *(const s16x8*)&Bs[b][kc][r * 32 + cc * 8];
      }
#pragma unroll
      for (int mt = 0; mt < 8; ++mt) {
        const int r = wm * 128 + mt * 16 + lm;
        const int cc = quad ^ (r & 3);
        afrag[mt] = *(const s16x8*)&As[b][kc][r * 32 + cc * 8];
      }

      __builtin_amdgcn_s_setprio(1);
#pragma unroll
      for (int mt = 0; mt < 8; ++mt)
#pragma unroll
        for (int nt = 0; nt < 4; ++nt)
          acc[mt][nt] = mfma16(afrag[mt], bfrag[nt], acc[mt][nt]);
      __builtin_amdgcn_s_setprio(0);
    }
  }

  // epilogue: C write (same fragment->C mapping as k_gemm_lds, verified)
#pragma unroll
  for (int mt = 0; mt < 8; ++mt)
#pragma unroll
    for (int nt = 0; nt < 4; ++nt)
#pragma unroll
      for (int r = 0; r < 4; ++r)
        C[(m0 + wm * 128 + mt * 16 + quad * 4 + r) * ldc +
          n0 + wn * 64 + nt * 16 + lm] = f2bf(acc[mt][nt][r]);
}

// ---------------- causal flash attention, v4 ----------------------------
// 64-key tiles, causal pairing {pair, 31-pair} (33 uniform iters/block),
// DMA double-buffered K/V staging via global_load_lds (no VGPR round-trip,
// no spill), 1 barrier/iter. Unpadded LDS tiles use a global-side XOR
// swizzle (chunk cc = p ^ (row&7)) so b128 reads are bank-conflict-free.
__global__ __launch_bounds__(256) void k_attn(u16* __restrict__ qkv,
                                              const u16* __restrict__ vt) {
  __shared__ __attribute__((aligned(16))) u16 Ks[2][64 * 128];  // 2x16 KB, swizzled
  __shared__ __attribute__((aligned(16))) u16 Vs[2][128 * 64];  // 2x16 KB, swizzled
  __shared__ __attribute__((aligned(16))) u16 Ps[4 * 16 * 72];  //    9 KB
  const int bh = blockIdx.x, pair = blockIdx.y;
  const int b = bh >> 4, h = bh & 15;
  const int tid = threadIdx.x;
  const int lane = tid & 63, wave = tid >> 6;
  const int lm = lane & 15, quad = lane >> 4;
  const int pbase = wave * 1152;
  const int sw = lm & 7;  // read-side swizzle term
  const f32x4 fzero = {0.f, 0.f, 0.f, 0.f};

  const int phase_end = pair;  // it 0..pair: qtile=pair; it pair+1..32: qtile=31-pair

  // async-DMA K/V tile kt0 into buffer `buf` (global-side XOR swizzle)
  auto dma_tile = [&](int kt0, int buf) {
#pragma unroll
    for (int i = 0; i < 4; ++i) {  // K: [64 rows][128 u16], 16 rows/issue
      const int row = i * 16 + wave * 4 + (lane >> 4);
      const int cc = (lane & 15) ^ (row & 7);
      gl_lds16(&qkv[(b * 2048 + kt0 + row) * 6144 + 2048 + h * 128 + cc * 8],
               &Ks[buf][(i * 16 + wave * 4) * 128]);
    }
#pragma unroll
    for (int i = 0; i < 4; ++i) {  // V^T: [128 rows][64 u16], 32 rows/issue
      const int row = i * 32 + wave * 8 + (lane >> 3);
      const int cc = (lane & 7) ^ (row & 7);
      gl_lds16(&vt[bh * 262144 + row * 2048 + kt0 + cc * 8],
               &Vs[buf][(i * 32 + wave * 8) * 64]);
    }
  };

  // ---- prologue: stage tile for it=0 (kt=0) into buf 0 ----
  dma_tile(0, 0);

  // ---- phase-0 state (qtile = pair) ----
  int qtile = pair;
  int qb = qtile * 64;
  int qrow = qb + wave * 16 + lm;
  int qoff = (b * 2048 + qrow) * 6144 + h * 128;
  s16x8 qfrag[4];
#pragma unroll
  for (int c = 0; c < 4; ++c)
    qfrag[c] = *(const s16x8*)&qkv[qoff + c * 32 + quad * 8];
  f32x4 o[8];
#pragma unroll
  for (int dt = 0; dt < 8; ++dt) o[dt] = fzero;
  float m_run = NEG_BIG, l_run = 0.f;

  __syncthreads();  // buf0 DMA drained (vmcnt0 before barrier release)

  for (int it = 0; it < 33; ++it) {
    const int kt0 = (it <= phase_end ? it : it - phase_end - 1) * 64;
    const int buf = it & 1;

    // issue next tile's DMA into the other buffer (latency hidden by compute)
    if (it < 32) {
      const int nkt = (it + 1 <= phase_end ? it + 1 : it - phase_end) * 64;
      dma_tile(nkt, buf ^ 1);
    }

    // ---- S^T = K * Q^T on buf ----
    f32x4 sa[4];
#pragma unroll
    for (int ss = 0; ss < 4; ++ss) sa[ss] = fzero;
#pragma unroll
    for (int ss = 0; ss < 4; ++ss)
#pragma unroll
      for (int c = 0; c < 4; ++c) {
        const int ccs = (c * 4 + quad) ^ sw;
        s16x8 a = *(const s16x8*)&Ks[buf][(ss * 16 + lm) * 128 + ccs * 8];
        sa[ss] = mfma16(a, qfrag[c], sa[ss]);
      }

    // ---- scale + causal mask + online softmax (per column q = lm) ----
    float p[4][4];
    float vmax = NEG_BIG;
#pragma unroll
    for (int ss = 0; ss < 4; ++ss)
#pragma unroll
      for (int r = 0; r < 4; ++r) {
        const int kg = kt0 + ss * 16 + quad * 4 + r;
        float v = sa[ss][r] * ATTN_SCALE;
        if (kg > qrow) v = NEG_BIG;
        p[ss][r] = v;
        vmax = fmaxf(vmax, v);
      }
    vmax = fmaxf(vmax, __shfl_xor(vmax, 16, 64));
    vmax = fmaxf(vmax, __shfl_xor(vmax, 32, 64));
    const float m_new = fmaxf(m_run, vmax);
    const float alpha = __expf(m_run - m_new);
    float rsum = 0.f;
#pragma unroll
    for (int ss = 0; ss < 4; ++ss)
#pragma unroll
      for (int r = 0; r < 4; ++r) {
        p[ss][r] = __expf(p[ss][r] - m_new);  // masked: exp(-huge) = 0
        rsum += p[ss][r];
      }
    rsum += __shfl_xor(rsum, 16, 64);
    rsum += __shfl_xor(rsum, 32, 64);
    l_run = l_run * alpha + rsum;
    m_run = m_new;
#pragma unroll
    for (int dt = 0; dt < 8; ++dt) o[dt] *= alpha;

    // ---- P -> wave-private LDS bounce (intra-wave ordering, no barrier) --
#pragma unroll
    for (int ss = 0; ss < 4; ++ss)
#pragma unroll
      for (int r = 0; r < 4; ++r)
        Ps[pbase + lm * 72 + ss * 16 + quad * 4 + r] = f2bf(p[ss][r]);
    const s16x8 pv0 = *(const s16x8*)&Ps[pbase + lm * 72 + quad * 8];
    const s16x8 pv1 = *(const s16x8*)&Ps[pbase + lm * 72 + 32 + quad * 8];

    // ---- O^T += V^T * P^T over the two 32-key halves ----
#pragma unroll
    for (int dt = 0; dt < 8; ++dt) {
      const int c0 = (quad ^ sw) * 8, c1 = ((4 + quad) ^ sw) * 8;
      s16x8 a0 = *(const s16x8*)&Vs[buf][(dt * 16 + lm) * 64 + c0];
      s16x8 a1 = *(const s16x8*)&Vs[buf][(dt * 16 + lm) * 64 + c1];
      o[dt] = mfma16(a1, pv1, mfma16(a0, pv0, o[dt]));
    }

    // ---- phase boundary: write phase-0 output, reset for phase 1 ----
    if (it == phase_end) {
      const float inv_l = 1.0f / l_run;
#pragma unroll
      for (int dt = 0; dt < 8; ++dt)
#pragma unroll
        for (int r = 0; r < 4; ++r)
          qkv[qoff + dt * 16 + quad * 4 + r] = f2bf(o[dt][r] * inv_l);
      qtile = 31 - pair;
      qb = qtile * 64;
      qrow = qb + wave * 16 + lm;
      qoff = (b * 2048 + qrow) * 6144 + h * 128;
#pragma unroll
      for (int c = 0; c < 4; ++c)
        qfrag[c] = *(const s16x8*)&qkv[qoff + c * 32 + quad * 8];
#pragma unroll
      for (int dt = 0; dt < 8; ++dt) o[dt] = fzero;
      m_run = NEG_BIG; l_run = 0.f;
    }

    // single barrier: drains this iter's DMA (vmcnt0) + guards buf reuse
    if (it < 32) __syncthreads();
  }

  // ---- phase-1 epilogue ----
  const float inv_l = 1.0f / l_run;
#pragma unroll
  for (int dt = 0; dt < 8; ++dt)
#pragma unroll
    for (int r = 0; r < 4; ++r)
      qkv[qoff + dt * 16 + quad * 4 + r] = f2bf(o[dt][r] * inv_l);
}

// ---------------- host launcher ----------------------------------------
extern "C" void kernel_launch(void* const* d_in, const int* in_sizes, int n_in,
                              void* d_out, int out_size, void* d_ws, size_t ws_size,
                              hipStream_t stream) {
  const float* hidden = (const float*)d_in[0];  // [4096][2048] fp32
  const float* w_qkv  = (const float*)d_in[1];  // [2048][6144] fp32
  const float* w_o    = (const float*)d_in[2];  // [2048][2048] fp32
  float* out = (float*)d_out;                   // [4096][2048] fp32
  u16* ws = (u16*)d_ws;

  u16* qkv   = ws;
  u16* wqkvT = ws + 25165824;
  u16* vt    = ws + 25165824;
  u16* woT   = ws + 33554432;
  u16* hb    = ws + 37748736;
  const bool fast = ws_size >= (size_t)46137344 * 2;

  dim3 tb(32, 8);
  k_transpose_cast<<<dim3(192, 64), tb, 0, stream>>>(w_qkv, wqkvT, 2048, 6144);
  if (fast) {
    k_cast<<<8192, 256, 0, stream>>>(hidden, hb, 2097152);
    k_gemm256<<<384, 512, 0, stream>>>(hb, wqkvT, qkv, 6144);
  } else {
    k_gemm_lds<true, u16><<<dim3(48, 32), 256, 0, stream>>>(hidden, 2048, wqkvT,
                                                            qkv, 6144, 2048);
  }
  k_rope<<<32768, 256, 0, stream>>>(qkv);
  k_vtrans<<<dim3(64, 4, 32), tb, 0, stream>>>(qkv, vt);
  k_transpose_cast<<<dim3(64, 64), tb, 0, stream>>>(w_o, woT, 2048, 2048);
  k_attn<<<dim3(32, 16), 256, 0, stream>>>(qkv, vt);  // x=bh (XCD locality)
  k_gemm_lds<false, float><<<dim3(16, 32), 256, 0, stream>>>(qkv, 6144, woT,
                                                             out, 2048, 2048);
}

// Round 4
// 420.185 us; speedup vs baseline: 1.0820x; 1.0820x over previous
//
#include <hip/hip_runtime.h>
#include <math.h>

typedef unsigned short u16;
typedef short s16x8 __attribute__((ext_vector_type(8)));  // 8 bf16 lanes (4 VGPRs)
typedef float f32x4 __attribute__((ext_vector_type(4)));

// B=2, S=2048, D=2048, H=16, HD=128; qkv row width = 6144
#define ATTN_SCALE 0.08838834764831845f
#define NEG_BIG -1.0e30f

__device__ __forceinline__ u16 f2bf(float f) {
  union { float f; unsigned u; } c; c.f = f;
  return (u16)((c.u + 0x7fffu + ((c.u >> 16) & 1u)) >> 16);  // RNE
}
__device__ __forceinline__ float bf2f(u16 v) {
  union { unsigned u; float f; } c; c.u = ((unsigned)v) << 16;
  return c.f;
}
__device__ __forceinline__ f32x4 mfma16(s16x8 a, s16x8 b, f32x4 c) {
  return __builtin_amdgcn_mfma_f32_16x16x32_bf16(a, b, c, 0, 0, 0);
}
// async global->LDS DMA, 16 B/lane; LDS dest = wave-uniform base + lane*16
__device__ __forceinline__ void gl_lds16(const u16* g, u16* l) {
  __builtin_amdgcn_global_load_lds(
      (const __attribute__((address_space(1))) unsigned int*)g,
      (__attribute__((address_space(3))) unsigned int*)l, 16, 0, 0);
}

// -------- fp32 -> bf16 elementwise cast (float4 vectorized) -------------
__global__ __launch_bounds__(256) void k_cast(const float* __restrict__ in,
                                              u16* __restrict__ out, int n4) {
  const int i = blockIdx.x * 256 + threadIdx.x;
  if (i >= n4) return;
  const float4 v = ((const float4*)in)[i];
  ushort4 o;
  o.x = f2bf(v.x); o.y = f2bf(v.y); o.z = f2bf(v.z); o.w = f2bf(v.w);
  ((ushort4*)out)[i] = o;
}

// -------- fp32 [R][C] -> bf16 out[C][R] transpose+cast ------------------
__global__ __launch_bounds__(256) void k_transpose_cast(const float* __restrict__ in,
                                                        u16* __restrict__ out,
                                                        int R, int C) {
  __shared__ __attribute__((aligned(16))) u16 tile[32][33];
  const int c0 = blockIdx.x * 32, r0 = blockIdx.y * 32;
  const int tx = threadIdx.x, ty = threadIdx.y;
#pragma unroll
  for (int i = 0; i < 4; ++i)
    tile[ty + 8 * i][tx] = f2bf(in[(r0 + ty + 8 * i) * C + c0 + tx]);
  __syncthreads();
#pragma unroll
  for (int i = 0; i < 4; ++i)
    out[(c0 + ty + 8 * i) * R + r0 + tx] = tile[tx][ty + 8 * i];
}

// ---------------- V -> V^T per (b,h): vt[bh][d][s] = qkv_v[b,s,h,d] ------
__global__ __launch_bounds__(256) void k_vtrans(const u16* __restrict__ qkv,
                                                u16* __restrict__ vt) {
  __shared__ __attribute__((aligned(16))) u16 tile[32][33];
  const int bh = blockIdx.z, b = bh >> 4, h = bh & 15;
  const int s0 = blockIdx.x * 32, d0 = blockIdx.y * 32;
  const int tx = threadIdx.x, ty = threadIdx.y;
#pragma unroll
  for (int i = 0; i < 4; ++i) {
    const int s = s0 + ty + 8 * i;
    tile[ty + 8 * i][tx] = qkv[(b * 2048 + s) * 6144 + 4096 + h * 128 + d0 + tx];
  }
  __syncthreads();
#pragma unroll
  for (int i = 0; i < 4; ++i) {
    const int d = d0 + ty + 8 * i;
    vt[bh * 262144 + d * 2048 + s0 + tx] = tile[tx][ty + 8 * i];
  }
}

// ---------------- RoPE in-place on Q and K sections of qkv (bf16) -------
__global__ __launch_bounds__(256) void k_rope(u16* __restrict__ qkv) {
  const int id = blockIdx.x * 256 + threadIdx.x;  // 8,388,608 threads
  const int j = id & 63;
  const int h = (id >> 6) & 15;
  const int sec = (id >> 10) & 1;
  const int m = id >> 11;  // b*2048+s
  const int s = m & 2047;
  const int base = m * 6144 + sec * 2048 + h * 128 + j;
  const float q0 = bf2f(qkv[base]);
  const float q1 = bf2f(qkv[base + 64]);
  const float inv = exp2f((float)j * -0.20762050593046014f);  // 10000^(-j/64)
  const float ang = (float)s * inv;
  float c, sn;
  sincosf(ang, &sn, &c);  // sincosf(x, SIN*, COS*) — sin FIRST
  qkv[base]      = f2bf(q0 * c - q1 * sn);
  qkv[base + 64] = f2bf(q1 * c + q0 * sn);
}

// ------- GEMM (m97 structure): C[M][N] = A[M][K] * BT[N][K]^T -----------
// kept for the fp32-A fallback path and the W_o GEMM.
template <bool A_F32, typename OUT_T>
__global__ __launch_bounds__(256) void k_gemm_lds(const void* __restrict__ Ap, int lda,
                                                  const u16* __restrict__ BT,
                                                  OUT_T* __restrict__ C, int ldc,
                                                  int K) {
  __shared__ __attribute__((aligned(16))) u16 As[128 * 32];
  __shared__ __attribute__((aligned(16))) u16 Bs[128 * 32];
  const int tid = threadIdx.x;
  const int lane = tid & 63, wave = tid >> 6;
  const int lm = lane & 15, quad = lane >> 4;
  const int wm = wave >> 1, wn = wave & 1;
  const int m0 = blockIdx.y * 128, n0 = blockIdx.x * 128;
  const int srow = lane >> 2, scol = (lane & 3) * 8;  // staging map

  const f32x4 fzero = {0.f, 0.f, 0.f, 0.f};
  f32x4 acc[4][4];
#pragma unroll
  for (int i = 0; i < 4; ++i)
#pragma unroll
    for (int j = 0; j < 4; ++j) acc[i][j] = fzero;

  for (int k0 = 0; k0 < K; k0 += 32) {
    __syncthreads();
    if constexpr (A_F32) {
      const float* Af = (const float*)Ap;
#pragma unroll
      for (int i = 0; i < 2; ++i) {
        const int seg = tid + 256 * i;
        const int row = seg >> 2, c8 = (seg & 3) * 8;
        const float4 u = *(const float4*)&Af[(m0 + row) * lda + k0 + c8];
        const float4 w = *(const float4*)&Af[(m0 + row) * lda + k0 + c8 + 4];
        uint4 pk;
        pk.x = (unsigned)f2bf(u.x) | ((unsigned)f2bf(u.y) << 16);
        pk.y = (unsigned)f2bf(u.z) | ((unsigned)f2bf(u.w) << 16);
        pk.z = (unsigned)f2bf(w.x) | ((unsigned)f2bf(w.y) << 16);
        pk.w = (unsigned)f2bf(w.z) | ((unsigned)f2bf(w.w) << 16);
        *(uint4*)&As[row * 32 + c8] = pk;
      }
#pragma unroll
      for (int j = 0; j < 2; ++j) {
        const int rb = wave * 32 + j * 16;
        gl_lds16(&BT[(n0 + rb + srow) * K + k0 + scol], &Bs[rb * 32]);
      }
    } else {
      const u16* Ab = (const u16*)Ap;
#pragma unroll
      for (int j = 0; j < 2; ++j) {
        const int rb = wave * 32 + j * 16;
        gl_lds16(&Ab[(m0 + rb + srow) * lda + k0 + scol], &As[rb * 32]);
        gl_lds16(&BT[(n0 + rb + srow) * K + k0 + scol], &Bs[rb * 32]);
      }
    }
    __syncthreads();  // drains vmcnt (DMA) + lgkmcnt before reads

    s16x8 af[4], bfr[4];
#pragma unroll
    for (int t = 0; t < 4; ++t) {
      af[t]  = *(const s16x8*)&As[(wm * 64 + t * 16 + lm) * 32 + quad * 8];
      bfr[t] = *(const s16x8*)&Bs[(wn * 64 + t * 16 + lm) * 32 + quad * 8];
    }
#pragma unroll
    for (int mt = 0; mt < 4; ++mt)
#pragma unroll
      for (int nt = 0; nt < 4; ++nt)
        acc[mt][nt] = mfma16(af[mt], bfr[nt], acc[mt][nt]);
  }
#pragma unroll
  for (int mt = 0; mt < 4; ++mt)
#pragma unroll
    for (int nt = 0; nt < 4; ++nt)
#pragma unroll
      for (int r = 0; r < 4; ++r) {
        const float v = acc[mt][nt][r];
        const int idx = (m0 + wm * 64 + mt * 16 + quad * 4 + r) * ldc +
                        n0 + wn * 64 + nt * 16 + lm;
        if constexpr (sizeof(OUT_T) == 2) C[idx] = f2bf(v);
        else                              C[idx] = v;
      }
}

// ------- 256x256 GEMM v2: two-barrier phases, 3-deep counted pipeline ---
// C[M][N] = A[M][K] * BT[N][K]^T, bf16 in/out. K=2048 = 64 units of BK=32.
// 8 waves (2M x 4N), per-wave 128x64 output. LDS 96 KiB = 3 rotating units
// (A[256][32] + B[256][32] each). m201-style phase: {12 ds_read_b128 from
// buf[u%3] || issue stage(u+2) -> buf[(u+2)%3]} -> vmcnt(4) -> barrier ->
// lgkmcnt(0) + sched_barrier -> setprio(1) 32 MFMA setprio(0) -> barrier.
// Ledger: stage(u) issued @u-2, certified @u-1 mid vmcnt(4) (only
// stage(u+1) outstanding); never vmcnt(0) except final drain @u=62.
// WAR hazard: stage(u+2) targets buf read @u-1, whose reads retired at
// u-1's lgkmcnt(0), separated by u-1's trailing barrier. Swizzle: linear
// LDS dest + inverse-swizzled global source (gc = c ^ (r&3)) + matching
// read (rule #21) — math verified on-harness in round 3.
__global__ __launch_bounds__(512, 2) void k_gemm256(const u16* __restrict__ A,
                                                    const u16* __restrict__ BT,
                                                    u16* __restrict__ C, int ldc) {
  __shared__ __attribute__((aligned(16))) u16 As[3][256 * 32];
  __shared__ __attribute__((aligned(16))) u16 Bs[3][256 * 32];
  const int K = 2048;
  const int tid = threadIdx.x;
  const int lane = tid & 63, wave = tid >> 6;
  const int lm = lane & 15, quad = lane >> 4;
  const int wm = wave >> 2, wn = wave & 3;  // 2M x 4N wave grid

  // XCD-aware swizzle (grid=384, 384%8==0 -> bijective). Column-major tile
  // map: consecutive swizzled ids share the B panel.
  int bid = (blockIdx.x & 7) * (gridDim.x >> 3) + (blockIdx.x >> 3);
  const int m0 = (bid & 15) * 256;  // M=4096 -> 16 tiles
  const int n0 = (bid >> 4) * 256;  // N=6144 -> 24 tiles

  // stage unit u (BK=32 K-slice of A and B) into rotating buffer bi
  auto stage_unit = [&](int u, int bi) {
    const int k0 = u * 32;
#pragma unroll
    for (int i = 0; i < 2; ++i) {
      const int r = i * 128 + 16 * wave + (lane >> 2);  // row within tile
      const int gc = (lane & 3) ^ (r & 3);              // inverse swizzle
      gl_lds16(&A[(m0 + r) * K + k0 + gc * 8],
               &As[bi][(i * 128 + 16 * wave) * 32]);
      gl_lds16(&BT[(n0 + r) * K + k0 + gc * 8],
               &Bs[bi][(i * 128 + 16 * wave) * 32]);
    }
  };

  const f32x4 fzero = {0.f, 0.f, 0.f, 0.f};
  f32x4 acc[8][4];
#pragma unroll
  for (int i = 0; i < 8; ++i)
#pragma unroll
    for (int j = 0; j < 4; ++j) acc[i][j] = fzero;

  // prologue: units 0,1 in flight (8 issues); certify unit 0, keep unit 1
  stage_unit(0, 0);
  stage_unit(1, 1);
  asm volatile("s_waitcnt vmcnt(4)" ::: "memory");
  __builtin_amdgcn_s_barrier();

  int bi = 0;
  for (int u = 0; u < 64; ++u) {
    // ---- open region: fragment reads (12 ds_read_b128) + prefetch issue
    s16x8 bfrag[4], afrag[8];
#pragma unroll
    for (int nt = 0; nt < 4; ++nt) {
      const int r = wn * 64 + nt * 16 + lm;
      const int cc = quad ^ (r & 3);
      bfrag[nt] = *(const s16x8*)&Bs[bi][r * 32 + cc * 8];
    }
#pragma unroll
    for (int mt = 0; mt < 8; ++mt) {
      const int r = wm * 128 + mt * 16 + lm;
      const int cc = quad ^ (r & 3);
      afrag[mt] = *(const s16x8*)&As[bi][r * 32 + cc * 8];
    }
    if (u < 62) {
      int bi2 = bi + 2; if (bi2 >= 3) bi2 -= 3;
      stage_unit(u + 2, bi2);
    }

    // ---- mid: counted certification of unit u+1 (never drain to 0
    // except the final u=62 epilogue wait; u=63 has nothing outstanding)
    if (u < 62)       asm volatile("s_waitcnt vmcnt(4)" ::: "memory");
    else if (u == 62) asm volatile("s_waitcnt vmcnt(0)" ::: "memory");
    __builtin_amdgcn_s_barrier();
    asm volatile("s_waitcnt lgkmcnt(0)" ::: "memory");
    __builtin_amdgcn_sched_barrier(0);

    // ---- pure-MFMA region
    __builtin_amdgcn_s_setprio(1);
#pragma unroll
    for (int mt = 0; mt < 8; ++mt)
#pragma unroll
      for (int nt = 0; nt < 4; ++nt)
        acc[mt][nt] = mfma16(afrag[mt], bfrag[nt], acc[mt][nt]);
    __builtin_amdgcn_s_setprio(0);
    if (u < 63) __builtin_amdgcn_s_barrier();

    bi = (bi == 2) ? 0 : bi + 1;
  }

  // epilogue: C write (fragment->C mapping harness-verified)
#pragma unroll
  for (int mt = 0; mt < 8; ++mt)
#pragma unroll
    for (int nt = 0; nt < 4; ++nt)
#pragma unroll
      for (int r = 0; r < 4; ++r)
        C[(m0 + wm * 128 + mt * 16 + quad * 4 + r) * ldc +
          n0 + wn * 64 + nt * 16 + lm] = f2bf(acc[mt][nt][r]);
}

// ---------------- causal flash attention, v4 ----------------------------
// 64-key tiles, causal pairing {pair, 31-pair} (33 uniform iters/block),
// DMA double-buffered K/V staging via global_load_lds (no VGPR round-trip,
// no spill), 1 barrier/iter. Unpadded LDS tiles use a global-side XOR
// swizzle (chunk cc = p ^ (row&7)) so b128 reads are bank-conflict-free.
__global__ __launch_bounds__(256) void k_attn(u16* __restrict__ qkv,
                                              const u16* __restrict__ vt) {
  __shared__ __attribute__((aligned(16))) u16 Ks[2][64 * 128];  // 2x16 KB, swizzled
  __shared__ __attribute__((aligned(16))) u16 Vs[2][128 * 64];  // 2x16 KB, swizzled
  __shared__ __attribute__((aligned(16))) u16 Ps[4 * 16 * 72];  //    9 KB
  const int bh = blockIdx.x, pair = blockIdx.y;
  const int b = bh >> 4, h = bh & 15;
  const int tid = threadIdx.x;
  const int lane = tid & 63, wave = tid >> 6;
  const int lm = lane & 15, quad = lane >> 4;
  const int pbase = wave * 1152;
  const int sw = lm & 7;  // read-side swizzle term
  const f32x4 fzero = {0.f, 0.f, 0.f, 0.f};

  const int phase_end = pair;  // it 0..pair: qtile=pair; it pair+1..32: qtile=31-pair

  // async-DMA K/V tile kt0 into buffer `buf` (global-side XOR swizzle)
  auto dma_tile = [&](int kt0, int buf) {
#pragma unroll
    for (int i = 0; i < 4; ++i) {  // K: [64 rows][128 u16], 16 rows/issue
      const int row = i * 16 + wave * 4 + (lane >> 4);
      const int cc = (lane & 15) ^ (row & 7);
      gl_lds16(&qkv[(b * 2048 + kt0 + row) * 6144 + 2048 + h * 128 + cc * 8],
               &Ks[buf][(i * 16 + wave * 4) * 128]);
    }
#pragma unroll
    for (int i = 0; i < 4; ++i) {  // V^T: [128 rows][64 u16], 32 rows/issue
      const int row = i * 32 + wave * 8 + (lane >> 3);
      const int cc = (lane & 7) ^ (row & 7);
      gl_lds16(&vt[bh * 262144 + row * 2048 + kt0 + cc * 8],
               &Vs[buf][(i * 32 + wave * 8) * 64]);
    }
  };

  // ---- prologue: stage tile for it=0 (kt=0) into buf 0 ----
  dma_tile(0, 0);

  // ---- phase-0 state (qtile = pair) ----
  int qtile = pair;
  int qb = qtile * 64;
  int qrow = qb + wave * 16 + lm;
  int qoff = (b * 2048 + qrow) * 6144 + h * 128;
  s16x8 qfrag[4];
#pragma unroll
  for (int c = 0; c < 4; ++c)
    qfrag[c] = *(const s16x8*)&qkv[qoff + c * 32 + quad * 8];
  f32x4 o[8];
#pragma unroll
  for (int dt = 0; dt < 8; ++dt) o[dt] = fzero;
  float m_run = NEG_BIG, l_run = 0.f;

  __syncthreads();  // buf0 DMA drained (vmcnt0 before barrier release)

  for (int it = 0; it < 33; ++it) {
    const int kt0 = (it <= phase_end ? it : it - phase_end - 1) * 64;
    const int buf = it & 1;

    // issue next tile's DMA into the other buffer (latency hidden by compute)
    if (it < 32) {
      const int nkt = (it + 1 <= phase_end ? it + 1 : it - phase_end) * 64;
      dma_tile(nkt, buf ^ 1);
    }

    // ---- S^T = K * Q^T on buf ----
    f32x4 sa[4];
#pragma unroll
    for (int ss = 0; ss < 4; ++ss) sa[ss] = fzero;
#pragma unroll
    for (int ss = 0; ss < 4; ++ss)
#pragma unroll
      for (int c = 0; c < 4; ++c) {
        const int ccs = (c * 4 + quad) ^ sw;
        s16x8 a = *(const s16x8*)&Ks[buf][(ss * 16 + lm) * 128 + ccs * 8];
        sa[ss] = mfma16(a, qfrag[c], sa[ss]);
      }

    // ---- scale + causal mask + online softmax (per column q = lm) ----
    float p[4][4];
    float vmax = NEG_BIG;
#pragma unroll
    for (int ss = 0; ss < 4; ++ss)
#pragma unroll
      for (int r = 0; r < 4; ++r) {
        const int kg = kt0 + ss * 16 + quad * 4 + r;
        float v = sa[ss][r] * ATTN_SCALE;
        if (kg > qrow) v = NEG_BIG;
        p[ss][r] = v;
        vmax = fmaxf(vmax, v);
      }
    vmax = fmaxf(vmax, __shfl_xor(vmax, 16, 64));
    vmax = fmaxf(vmax, __shfl_xor(vmax, 32, 64));
    const float m_new = fmaxf(m_run, vmax);
    const float alpha = __expf(m_run - m_new);
    float rsum = 0.f;
#pragma unroll
    for (int ss = 0; ss < 4; ++ss)
#pragma unroll
      for (int r = 0; r < 4; ++r) {
        p[ss][r] = __expf(p[ss][r] - m_new);  // masked: exp(-huge) = 0
        rsum += p[ss][r];
      }
    rsum += __shfl_xor(rsum, 16, 64);
    rsum += __shfl_xor(rsum, 32, 64);
    l_run = l_run * alpha + rsum;
    m_run = m_new;
#pragma unroll
    for (int dt = 0; dt < 8; ++dt) o[dt] *= alpha;

    // ---- P -> wave-private LDS bounce (intra-wave ordering, no barrier) --
#pragma unroll
    for (int ss = 0; ss < 4; ++ss)
#pragma unroll
      for (int r = 0; r < 4; ++r)
        Ps[pbase + lm * 72 + ss * 16 + quad * 4 + r] = f2bf(p[ss][r]);
    const s16x8 pv0 = *(const s16x8*)&Ps[pbase + lm * 72 + quad * 8];
    const s16x8 pv1 = *(const s16x8*)&Ps[pbase + lm * 72 + 32 + quad * 8];

    // ---- O^T += V^T * P^T over the two 32-key halves ----
#pragma unroll
    for (int dt = 0; dt < 8; ++dt) {
      const int c0 = (quad ^ sw) * 8, c1 = ((4 + quad) ^ sw) * 8;
      s16x8 a0 = *(const s16x8*)&Vs[buf][(dt * 16 + lm) * 64 + c0];
      s16x8 a1 = *(const s16x8*)&Vs[buf][(dt * 16 + lm) * 64 + c1];
      o[dt] = mfma16(a1, pv1, mfma16(a0, pv0, o[dt]));
    }

    // ---- phase boundary: write phase-0 output, reset for phase 1 ----
    if (it == phase_end) {
      const float inv_l = 1.0f / l_run;
#pragma unroll
      for (int dt = 0; dt < 8; ++dt)
#pragma unroll
        for (int r = 0; r < 4; ++r)
          qkv[qoff + dt * 16 + quad * 4 + r] = f2bf(o[dt][r] * inv_l);
      qtile = 31 - pair;
      qb = qtile * 64;
      qrow = qb + wave * 16 + lm;
      qoff = (b * 2048 + qrow) * 6144 + h * 128;
#pragma unroll
      for (int c = 0; c < 4; ++c)
        qfrag[c] = *(const s16x8*)&qkv[qoff + c * 32 + quad * 8];
#pragma unroll
      for (int dt = 0; dt < 8; ++dt) o[dt] = fzero;
      m_run = NEG_BIG; l_run = 0.f;
    }

    // single barrier: drains this iter's DMA (vmcnt0) + guards buf reuse
    if (it < 32) __syncthreads();
  }

  // ---- phase-1 epilogue ----
  const float inv_l = 1.0f / l_run;
#pragma unroll
  for (int dt = 0; dt < 8; ++dt)
#pragma unroll
    for (int r = 0; r < 4; ++r)
      qkv[qoff + dt * 16 + quad * 4 + r] = f2bf(o[dt][r] * inv_l);
}

// ---------------- host launcher ----------------------------------------
extern "C" void kernel_launch(void* const* d_in, const int* in_sizes, int n_in,
                              void* d_out, int out_size, void* d_ws, size_t ws_size,
                              hipStream_t stream) {
  const float* hidden = (const float*)d_in[0];  // [4096][2048] fp32
  const float* w_qkv  = (const float*)d_in[1];  // [2048][6144] fp32
  const float* w_o    = (const float*)d_in[2];  // [2048][2048] fp32
  float* out = (float*)d_out;                   // [4096][2048] fp32
  u16* ws = (u16*)d_ws;

  u16* qkv   = ws;
  u16* wqkvT = ws + 25165824;
  u16* vt    = ws + 25165824;
  u16* woT   = ws + 33554432;
  u16* hb    = ws + 37748736;
  const bool fast = ws_size >= (size_t)46137344 * 2;

  dim3 tb(32, 8);
  k_transpose_cast<<<dim3(192, 64), tb, 0, stream>>>(w_qkv, wqkvT, 2048, 6144);
  if (fast) {
    k_cast<<<8192, 256, 0, stream>>>(hidden, hb, 2097152);
    k_gemm256<<<384, 512, 0, stream>>>(hb, wqkvT, qkv, 6144);
  } else {
    k_gemm_lds<true, u16><<<dim3(48, 32), 256, 0, stream>>>(hidden, 2048, wqkvT,
                                                            qkv, 6144, 2048);
  }
  k_rope<<<32768, 256, 0, stream>>>(qkv);
  k_vtrans<<<dim3(64, 4, 32), tb, 0, stream>>>(qkv, vt);
  k_transpose_cast<<<dim3(64, 64), tb, 0, stream>>>(w_o, woT, 2048, 2048);
  k_attn<<<dim3(32, 16), 256, 0, stream>>>(qkv, vt);  // x=bh (XCD locality)
  k_gemm_lds<false, float><<<dim3(16, 32), 256, 0, stream>>>(qkv, 6144, woT,
                                                             out, 2048, 2048);
}

// Round 5
// 416.063 us; speedup vs baseline: 1.0927x; 1.0099x over previous
//
#include <hip/hip_runtime.h>
#include <math.h>

typedef unsigned short u16;
typedef short s16x8 __attribute__((ext_vector_type(8)));  // 8 bf16 lanes (4 VGPRs)
typedef float f32x4 __attribute__((ext_vector_type(4)));

// B=2, S=2048, D=2048, H=16, HD=128; qkv row width = 6144
#define ATTN_SCALE 0.08838834764831845f
#define NEG_BIG -1.0e30f

__device__ __forceinline__ u16 f2bf(float f) {
  union { float f; unsigned u; } c; c.f = f;
  return (u16)((c.u + 0x7fffu + ((c.u >> 16) & 1u)) >> 16);  // RNE
}
__device__ __forceinline__ float bf2f(u16 v) {
  union { unsigned u; float f; } c; c.u = ((unsigned)v) << 16;
  return c.f;
}
__device__ __forceinline__ f32x4 mfma16(s16x8 a, s16x8 b, f32x4 c) {
  return __builtin_amdgcn_mfma_f32_16x16x32_bf16(a, b, c, 0, 0, 0);
}
// async global->LDS DMA, 16 B/lane; LDS dest = wave-uniform base + lane*16
__device__ __forceinline__ void gl_lds16(const u16* g, u16* l) {
  __builtin_amdgcn_global_load_lds(
      (const __attribute__((address_space(1))) unsigned int*)g,
      (__attribute__((address_space(3))) unsigned int*)l, 16, 0, 0);
}

// -------- fp32 -> bf16 elementwise cast (float4 vectorized) -------------
__global__ __launch_bounds__(256) void k_cast(const float* __restrict__ in,
                                              u16* __restrict__ out, int n4) {
  const int i = blockIdx.x * 256 + threadIdx.x;
  if (i >= n4) return;
  const float4 v = ((const float4*)in)[i];
  ushort4 o;
  o.x = f2bf(v.x); o.y = f2bf(v.y); o.z = f2bf(v.z); o.w = f2bf(v.w);
  ((ushort4*)out)[i] = o;
}

// -------- fp32 [R][C] -> bf16 out[C][R] transpose+cast ------------------
__global__ __launch_bounds__(256) void k_transpose_cast(const float* __restrict__ in,
                                                        u16* __restrict__ out,
                                                        int R, int C) {
  __shared__ __attribute__((aligned(16))) u16 tile[32][33];
  const int c0 = blockIdx.x * 32, r0 = blockIdx.y * 32;
  const int tx = threadIdx.x, ty = threadIdx.y;
#pragma unroll
  for (int i = 0; i < 4; ++i)
    tile[ty + 8 * i][tx] = f2bf(in[(r0 + ty + 8 * i) * C + c0 + tx]);
  __syncthreads();
#pragma unroll
  for (int i = 0; i < 4; ++i)
    out[(c0 + ty + 8 * i) * R + r0 + tx] = tile[tx][ty + 8 * i];
}

// ---------------- V -> V^T per (b,h): vt[bh][d][s] = qkv_v[b,s,h,d] ------
__global__ __launch_bounds__(256) void k_vtrans(const u16* __restrict__ qkv,
                                                u16* __restrict__ vt) {
  __shared__ __attribute__((aligned(16))) u16 tile[32][33];
  const int bh = blockIdx.z, b = bh >> 4, h = bh & 15;
  const int s0 = blockIdx.x * 32, d0 = blockIdx.y * 32;
  const int tx = threadIdx.x, ty = threadIdx.y;
#pragma unroll
  for (int i = 0; i < 4; ++i) {
    const int s = s0 + ty + 8 * i;
    tile[ty + 8 * i][tx] = qkv[(b * 2048 + s) * 6144 + 4096 + h * 128 + d0 + tx];
  }
  __syncthreads();
#pragma unroll
  for (int i = 0; i < 4; ++i) {
    const int d = d0 + ty + 8 * i;
    vt[bh * 262144 + d * 2048 + s0 + tx] = tile[tx][ty + 8 * i];
  }
}

// ---------------- RoPE in-place on Q and K sections of qkv (bf16) -------
__global__ __launch_bounds__(256) void k_rope(u16* __restrict__ qkv) {
  const int id = blockIdx.x * 256 + threadIdx.x;  // 8,388,608 threads
  const int j = id & 63;
  const int h = (id >> 6) & 15;
  const int sec = (id >> 10) & 1;
  const int m = id >> 11;  // b*2048+s
  const int s = m & 2047;
  const int base = m * 6144 + sec * 2048 + h * 128 + j;
  const float q0 = bf2f(qkv[base]);
  const float q1 = bf2f(qkv[base + 64]);
  const float inv = exp2f((float)j * -0.20762050593046014f);  // 10000^(-j/64)
  const float ang = (float)s * inv;
  float c, sn;
  sincosf(ang, &sn, &c);  // sincosf(x, SIN*, COS*) — sin FIRST
  qkv[base]      = f2bf(q0 * c - q1 * sn);
  qkv[base + 64] = f2bf(q1 * c + q0 * sn);
}

// ------- GEMM (m97 structure): C[M][N] = A[M][K] * BT[N][K]^T -----------
// kept for the fp32-A fallback path and the W_o GEMM.
template <bool A_F32, typename OUT_T>
__global__ __launch_bounds__(256) void k_gemm_lds(const void* __restrict__ Ap, int lda,
                                                  const u16* __restrict__ BT,
                                                  OUT_T* __restrict__ C, int ldc,
                                                  int K) {
  __shared__ __attribute__((aligned(16))) u16 As[128 * 32];
  __shared__ __attribute__((aligned(16))) u16 Bs[128 * 32];
  const int tid = threadIdx.x;
  const int lane = tid & 63, wave = tid >> 6;
  const int lm = lane & 15, quad = lane >> 4;
  const int wm = wave >> 1, wn = wave & 1;
  const int m0 = blockIdx.y * 128, n0 = blockIdx.x * 128;
  const int srow = lane >> 2, scol = (lane & 3) * 8;  // staging map

  const f32x4 fzero = {0.f, 0.f, 0.f, 0.f};
  f32x4 acc[4][4];
#pragma unroll
  for (int i = 0; i < 4; ++i)
#pragma unroll
    for (int j = 0; j < 4; ++j) acc[i][j] = fzero;

  for (int k0 = 0; k0 < K; k0 += 32) {
    __syncthreads();
    if constexpr (A_F32) {
      const float* Af = (const float*)Ap;
#pragma unroll
      for (int i = 0; i < 2; ++i) {
        const int seg = tid + 256 * i;
        const int row = seg >> 2, c8 = (seg & 3) * 8;
        const float4 u = *(const float4*)&Af[(m0 + row) * lda + k0 + c8];
        const float4 w = *(const float4*)&Af[(m0 + row) * lda + k0 + c8 + 4];
        uint4 pk;
        pk.x = (unsigned)f2bf(u.x) | ((unsigned)f2bf(u.y) << 16);
        pk.y = (unsigned)f2bf(u.z) | ((unsigned)f2bf(u.w) << 16);
        pk.z = (unsigned)f2bf(w.x) | ((unsigned)f2bf(w.y) << 16);
        pk.w = (unsigned)f2bf(w.z) | ((unsigned)f2bf(w.w) << 16);
        *(uint4*)&As[row * 32 + c8] = pk;
      }
#pragma unroll
      for (int j = 0; j < 2; ++j) {
        const int rb = wave * 32 + j * 16;
        gl_lds16(&BT[(n0 + rb + srow) * K + k0 + scol], &Bs[rb * 32]);
      }
    } else {
      const u16* Ab = (const u16*)Ap;
#pragma unroll
      for (int j = 0; j < 2; ++j) {
        const int rb = wave * 32 + j * 16;
        gl_lds16(&Ab[(m0 + rb + srow) * lda + k0 + scol], &As[rb * 32]);
        gl_lds16(&BT[(n0 + rb + srow) * K + k0 + scol], &Bs[rb * 32]);
      }
    }
    __syncthreads();  // drains vmcnt (DMA) + lgkmcnt before reads

    s16x8 af[4], bfr[4];
#pragma unroll
    for (int t = 0; t < 4; ++t) {
      af[t]  = *(const s16x8*)&As[(wm * 64 + t * 16 + lm) * 32 + quad * 8];
      bfr[t] = *(const s16x8*)&Bs[(wn * 64 + t * 16 + lm) * 32 + quad * 8];
    }
#pragma unroll
    for (int mt = 0; mt < 4; ++mt)
#pragma unroll
      for (int nt = 0; nt < 4; ++nt)
        acc[mt][nt] = mfma16(af[mt], bfr[nt], acc[mt][nt]);
  }
#pragma unroll
  for (int mt = 0; mt < 4; ++mt)
#pragma unroll
    for (int nt = 0; nt < 4; ++nt)
#pragma unroll
      for (int r = 0; r < 4; ++r) {
        const float v = acc[mt][nt][r];
        const int idx = (m0 + wm * 64 + mt * 16 + quad * 4 + r) * ldc +
                        n0 + wn * 64 + nt * 16 + lm;
        if constexpr (sizeof(OUT_T) == 2) C[idx] = f2bf(v);
        else                              C[idx] = v;
      }
}

// ------- 256x256 GEMM v3: faithful m201 8-phase schedule ----------------
// C[M][N] = A[M][K] * BT[N][K]^T, bf16 in/out. K=2048 = 32 K-tiles of 64.
// 8 waves (2M x 4N), wave tile 128x64. LDS 128 KiB: [buf][ks][256][32]
// k-half-split layout: 64-B rows -> DMA writes AND b128 fragment reads are
// bank-uniform with NO swizzle; each quarter (16 KB) is contiguous so the
// linear global_load_lds destination works directly.
// Per K-tile = 4 phases (q = ks*2 + mhalf). Phase: {reads: 4xB (q0/q2 only,
// regs persist 2 phases) + 4xA} -> stage 1 quarter of tile c+1 (2 gl_lds)
// -> [vmcnt(4) at q1/q3] -> barrier -> lgkmcnt(0) -> setprio(1) 16 MFMA
// setprio(0) -> barrier. Stagger overlap: barrier syncs ISSUE, lgkm(0) is
// per-wave COMPLETION -> MFMA starts drift across waves -> LDS pipe and
// matrix pipe overlap (the m201 mechanism my v2's coarse phases broke).
// Ledger (2 loads/stage/wave): at q3-end outstanding = {B_k0,A_k0,B_k1,
// A_k1}(c+1) = 8 -> vmcnt(4) certifies B_k0,A_k0 (needed q0/q1 next tile);
// at q1-end outstanding = {B_k1,A_k1}(c) + {B_k0,A_k0}(c+1) = 8 ->
// vmcnt(4) certifies B_k1,A_k1 (needed q2/q3). Never 0 until tile 31.
// WAR: stage targets opposite buffer, last read >=4 barriers earlier.
__global__ __launch_bounds__(512, 2) void k_gemm256(const u16* __restrict__ A,
                                                    const u16* __restrict__ BT,
                                                    u16* __restrict__ C, int ldc) {
  __shared__ __attribute__((aligned(16))) u16 As[2][2][256 * 32];
  __shared__ __attribute__((aligned(16))) u16 Bs[2][2][256 * 32];
  const int K = 2048;
  const int tid = threadIdx.x;
  const int lane = tid & 63, wave = tid >> 6;
  const int lm = lane & 15, quad = lane >> 4;
  const int wm = wave >> 2, wn = wave & 3;  // 2M x 4N wave grid

  // XCD-aware swizzle (grid=384, 384%8==0 -> bijective), column-major map.
  int bid = (blockIdx.x & 7) * (gridDim.x >> 3) + (blockIdx.x >> 3);
  const int m0 = (bid & 15) * 256;  // M=4096 -> 16 tiles
  const int n0 = (bid >> 4) * 256;  // N=6144 -> 24 tiles

  // stage one quarter (matrix: 0=B,1=A; k-half ks) of K-tile t.
  const int srow = lane >> 2, schunk = (lane & 3) * 8;
  auto stage_q = [&](int t, int matA, int ks) {
    const int buf = t & 1;
    const int k0 = t * 64 + ks * 32 + schunk;
    const u16* src = matA ? A : BT;
    const int gb = matA ? m0 : n0;
    u16* dst = matA ? &As[buf][ks][0] : &Bs[buf][ks][0];
#pragma unroll
    for (int j = 0; j < 2; ++j) {
      const int r0 = j * 128 + wave * 16;
      gl_lds16(&src[(gb + r0 + srow) * K + k0], dst + r0 * 32);
    }
  };

  const f32x4 fzero = {0.f, 0.f, 0.f, 0.f};
  f32x4 acc[8][4];
#pragma unroll
  for (int i = 0; i < 8; ++i)
#pragma unroll
    for (int j = 0; j < 4; ++j) acc[i][j] = fzero;

  // prologue: tile 0 quarters in steady stage order B_k0, A_k0, B_k1, A_k1
  stage_q(0, 0, 0); stage_q(0, 1, 0); stage_q(0, 0, 1); stage_q(0, 1, 1);
  asm volatile("s_waitcnt vmcnt(4)" ::: "memory");  // certify B_k0, A_k0
  asm volatile("s_barrier" ::: "memory");           // cross-wave visibility

  s16x8 bfr[4], afr[4];
  for (int c = 0; c < 32; ++c) {
    const int buf = c & 1;
#pragma unroll
    for (int q = 0; q < 4; ++q) {
      const int ks = q >> 1, mh = q & 1;
      // ---- fragment reads (B persists in regs across the phase pair)
      if (mh == 0) {
#pragma unroll
        for (int nt = 0; nt < 4; ++nt)
          bfr[nt] = *(const s16x8*)
              &Bs[buf][ks][(wn * 64 + nt * 16 + lm) * 32 + quad * 8];
      }
#pragma unroll
      for (int i = 0; i < 4; ++i)
        afr[i] = *(const s16x8*)
            &As[buf][ks][(wm * 128 + mh * 64 + i * 16 + lm) * 32 + quad * 8];
      // ---- stage one quarter of tile c+1 (q0:B_k0 q1:A_k0 q2:B_k1 q3:A_k1)
      if (c < 31) stage_q(c + 1, mh, ks);
      // ---- counted certification at q1/q3 ends (vmcnt(0) only last tile)
      if (mh == 1) {
        if (c == 31) { asm volatile("s_waitcnt vmcnt(0)" ::: "memory"); }
        else         { asm volatile("s_waitcnt vmcnt(4)" ::: "memory"); }
      }
      asm volatile("s_barrier" ::: "memory");
      asm volatile("s_waitcnt lgkmcnt(0)" ::: "memory");
      // ---- pure-MFMA cluster (16)
      __builtin_amdgcn_s_setprio(1);
#pragma unroll
      for (int i = 0; i < 4; ++i)
#pragma unroll
        for (int nt = 0; nt < 4; ++nt)
          acc[mh * 4 + i][nt] = mfma16(afr[i], bfr[nt], acc[mh * 4 + i][nt]);
      __builtin_amdgcn_s_setprio(0);
      asm volatile("s_barrier" ::: "memory");
    }
  }

  // epilogue: C write (fragment->C mapping harness-verified rounds 3-4)
#pragma unroll
  for (int mt = 0; mt < 8; ++mt)
#pragma unroll
    for (int nt = 0; nt < 4; ++nt)
#pragma unroll
      for (int r = 0; r < 4; ++r)
        C[(m0 + wm * 128 + mt * 16 + quad * 4 + r) * ldc +
          n0 + wn * 64 + nt * 16 + lm] = f2bf(acc[mt][nt][r]);
}

// ---------------- causal flash attention, v4 ----------------------------
// 64-key tiles, causal pairing {pair, 31-pair} (33 uniform iters/block),
// DMA double-buffered K/V staging via global_load_lds (no VGPR round-trip,
// no spill), 1 barrier/iter. Unpadded LDS tiles use a global-side XOR
// swizzle (chunk cc = p ^ (row&7)) so b128 reads are bank-conflict-free.
__global__ __launch_bounds__(256) void k_attn(u16* __restrict__ qkv,
                                              const u16* __restrict__ vt) {
  __shared__ __attribute__((aligned(16))) u16 Ks[2][64 * 128];  // 2x16 KB, swizzled
  __shared__ __attribute__((aligned(16))) u16 Vs[2][128 * 64];  // 2x16 KB, swizzled
  __shared__ __attribute__((aligned(16))) u16 Ps[4 * 16 * 72];  //    9 KB
  const int bh = blockIdx.x, pair = blockIdx.y;
  const int b = bh >> 4, h = bh & 15;
  const int tid = threadIdx.x;
  const int lane = tid & 63, wave = tid >> 6;
  const int lm = lane & 15, quad = lane >> 4;
  const int pbase = wave * 1152;
  const int sw = lm & 7;  // read-side swizzle term
  const f32x4 fzero = {0.f, 0.f, 0.f, 0.f};

  const int phase_end = pair;  // it 0..pair: qtile=pair; it pair+1..32: qtile=31-pair

  // async-DMA K/V tile kt0 into buffer `buf` (global-side XOR swizzle)
  auto dma_tile = [&](int kt0, int buf) {
#pragma unroll
    for (int i = 0; i < 4; ++i) {  // K: [64 rows][128 u16], 16 rows/issue
      const int row = i * 16 + wave * 4 + (lane >> 4);
      const int cc = (lane & 15) ^ (row & 7);
      gl_lds16(&qkv[(b * 2048 + kt0 + row) * 6144 + 2048 + h * 128 + cc * 8],
               &Ks[buf][(i * 16 + wave * 4) * 128]);
    }
#pragma unroll
    for (int i = 0; i < 4; ++i) {  // V^T: [128 rows][64 u16], 32 rows/issue
      const int row = i * 32 + wave * 8 + (lane >> 3);
      const int cc = (lane & 7) ^ (row & 7);
      gl_lds16(&vt[bh * 262144 + row * 2048 + kt0 + cc * 8],
               &Vs[buf][(i * 32 + wave * 8) * 64]);
    }
  };

  // ---- prologue: stage tile for it=0 (kt=0) into buf 0 ----
  dma_tile(0, 0);

  // ---- phase-0 state (qtile = pair) ----
  int qtile = pair;
  int qb = qtile * 64;
  int qrow = qb + wave * 16 + lm;
  int qoff = (b * 2048 + qrow) * 6144 + h * 128;
  s16x8 qfrag[4];
#pragma unroll
  for (int c = 0; c < 4; ++c)
    qfrag[c] = *(const s16x8*)&qkv[qoff + c * 32 + quad * 8];
  f32x4 o[8];
#pragma unroll
  for (int dt = 0; dt < 8; ++dt) o[dt] = fzero;
  float m_run = NEG_BIG, l_run = 0.f;

  __syncthreads();  // buf0 DMA drained (vmcnt0 before barrier release)

  for (int it = 0; it < 33; ++it) {
    const int kt0 = (it <= phase_end ? it : it - phase_end - 1) * 64;
    const int buf = it & 1;

    // issue next tile's DMA into the other buffer (latency hidden by compute)
    if (it < 32) {
      const int nkt = (it + 1 <= phase_end ? it + 1 : it - phase_end) * 64;
      dma_tile(nkt, buf ^ 1);
    }

    // ---- S^T = K * Q^T on buf ----
    f32x4 sa[4];
#pragma unroll
    for (int ss = 0; ss < 4; ++ss) sa[ss] = fzero;
#pragma unroll
    for (int ss = 0; ss < 4; ++ss)
#pragma unroll
      for (int c = 0; c < 4; ++c) {
        const int ccs = (c * 4 + quad) ^ sw;
        s16x8 a = *(const s16x8*)&Ks[buf][(ss * 16 + lm) * 128 + ccs * 8];
        sa[ss] = mfma16(a, qfrag[c], sa[ss]);
      }

    // ---- scale + causal mask + online softmax (per column q = lm) ----
    float p[4][4];
    float vmax = NEG_BIG;
#pragma unroll
    for (int ss = 0; ss < 4; ++ss)
#pragma unroll
      for (int r = 0; r < 4; ++r) {
        const int kg = kt0 + ss * 16 + quad * 4 + r;
        float v = sa[ss][r] * ATTN_SCALE;
        if (kg > qrow) v = NEG_BIG;
        p[ss][r] = v;
        vmax = fmaxf(vmax, v);
      }
    vmax = fmaxf(vmax, __shfl_xor(vmax, 16, 64));
    vmax = fmaxf(vmax, __shfl_xor(vmax, 32, 64));
    const float m_new = fmaxf(m_run, vmax);
    const float alpha = __expf(m_run - m_new);
    float rsum = 0.f;
#pragma unroll
    for (int ss = 0; ss < 4; ++ss)
#pragma unroll
      for (int r = 0; r < 4; ++r) {
        p[ss][r] = __expf(p[ss][r] - m_new);  // masked: exp(-huge) = 0
        rsum += p[ss][r];
      }
    rsum += __shfl_xor(rsum, 16, 64);
    rsum += __shfl_xor(rsum, 32, 64);
    l_run = l_run * alpha + rsum;
    m_run = m_new;
#pragma unroll
    for (int dt = 0; dt < 8; ++dt) o[dt] *= alpha;

    // ---- P -> wave-private LDS bounce (intra-wave ordering, no barrier) --
#pragma unroll
    for (int ss = 0; ss < 4; ++ss)
#pragma unroll
      for (int r = 0; r < 4; ++r)
        Ps[pbase + lm * 72 + ss * 16 + quad * 4 + r] = f2bf(p[ss][r]);
    const s16x8 pv0 = *(const s16x8*)&Ps[pbase + lm * 72 + quad * 8];
    const s16x8 pv1 = *(const s16x8*)&Ps[pbase + lm * 72 + 32 + quad * 8];

    // ---- O^T += V^T * P^T over the two 32-key halves ----
#pragma unroll
    for (int dt = 0; dt < 8; ++dt) {
      const int c0 = (quad ^ sw) * 8, c1 = ((4 + quad) ^ sw) * 8;
      s16x8 a0 = *(const s16x8*)&Vs[buf][(dt * 16 + lm) * 64 + c0];
      s16x8 a1 = *(const s16x8*)&Vs[buf][(dt * 16 + lm) * 64 + c1];
      o[dt] = mfma16(a1, pv1, mfma16(a0, pv0, o[dt]));
    }

    // ---- phase boundary: write phase-0 output, reset for phase 1 ----
    if (it == phase_end) {
      const float inv_l = 1.0f / l_run;
#pragma unroll
      for (int dt = 0; dt < 8; ++dt)
#pragma unroll
        for (int r = 0; r < 4; ++r)
          qkv[qoff + dt * 16 + quad * 4 + r] = f2bf(o[dt][r] * inv_l);
      qtile = 31 - pair;
      qb = qtile * 64;
      qrow = qb + wave * 16 + lm;
      qoff = (b * 2048 + qrow) * 6144 + h * 128;
#pragma unroll
      for (int c = 0; c < 4; ++c)
        qfrag[c] = *(const s16x8*)&qkv[qoff + c * 32 + quad * 8];
#pragma unroll
      for (int dt = 0; dt < 8; ++dt) o[dt] = fzero;
      m_run = NEG_BIG; l_run = 0.f;
    }

    // single barrier: drains this iter's DMA (vmcnt0) + guards buf reuse
    if (it < 32) __syncthreads();
  }

  // ---- phase-1 epilogue ----
  const float inv_l = 1.0f / l_run;
#pragma unroll
  for (int dt = 0; dt < 8; ++dt)
#pragma unroll
    for (int r = 0; r < 4; ++r)
      qkv[qoff + dt * 16 + quad * 4 + r] = f2bf(o[dt][r] * inv_l);
}

// ---------------- host launcher ----------------------------------------
extern "C" void kernel_launch(void* const* d_in, const int* in_sizes, int n_in,
                              void* d_out, int out_size, void* d_ws, size_t ws_size,
                              hipStream_t stream) {
  const float* hidden = (const float*)d_in[0];  // [4096][2048] fp32
  const float* w_qkv  = (const float*)d_in[1];  // [2048][6144] fp32
  const float* w_o    = (const float*)d_in[2];  // [2048][2048] fp32
  float* out = (float*)d_out;                   // [4096][2048] fp32
  u16* ws = (u16*)d_ws;

  u16* qkv   = ws;
  u16* wqkvT = ws + 25165824;
  u16* vt    = ws + 25165824;
  u16* woT   = ws + 33554432;
  u16* hb    = ws + 37748736;
  const bool fast = ws_size >= (size_t)46137344 * 2;

  dim3 tb(32, 8);
  k_transpose_cast<<<dim3(192, 64), tb, 0, stream>>>(w_qkv, wqkvT, 2048, 6144);
  if (fast) {
    k_cast<<<8192, 256, 0, stream>>>(hidden, hb, 2097152);
    k_gemm256<<<384, 512, 0, stream>>>(hb, wqkvT, qkv, 6144);
  } else {
    k_gemm_lds<true, u16><<<dim3(48, 32), 256, 0, stream>>>(hidden, 2048, wqkvT,
                                                            qkv, 6144, 2048);
  }
  k_rope<<<32768, 256, 0, stream>>>(qkv);
  k_vtrans<<<dim3(64, 4, 32), tb, 0, stream>>>(qkv, vt);
  k_transpose_cast<<<dim3(64, 64), tb, 0, stream>>>(w_o, woT, 2048, 2048);
  k_attn<<<dim3(32, 16), 256, 0, stream>>>(qkv, vt);  // x=bh (XCD locality)
  k_gemm_lds<false, float><<<dim3(16, 32), 256, 0, stream>>>(qkv, 6144, woT,
                                                             out, 2048, 2048);
}

// Round 6
// 405.665 us; speedup vs baseline: 1.1207x; 1.0256x over previous
//
#include <hip/hip_runtime.h>
#include <math.h>

typedef unsigned short u16;
typedef short s16x8 __attribute__((ext_vector_type(8)));  // 8 bf16 lanes (4 VGPRs)
typedef float f32x4 __attribute__((ext_vector_type(4)));

// B=2, S=2048, D=2048, H=16, HD=128; qkv row width = 6144
#define ATTN_SCALE 0.08838834764831845f
#define NEG_BIG -1.0e30f

__device__ __forceinline__ u16 f2bf(float f) {
  union { float f; unsigned u; } c; c.f = f;
  return (u16)((c.u + 0x7fffu + ((c.u >> 16) & 1u)) >> 16);  // RNE
}
__device__ __forceinline__ float bf2f(u16 v) {
  union { unsigned u; float f; } c; c.u = ((unsigned)v) << 16;
  return c.f;
}
__device__ __forceinline__ f32x4 mfma16(s16x8 a, s16x8 b, f32x4 c) {
  return __builtin_amdgcn_mfma_f32_16x16x32_bf16(a, b, c, 0, 0, 0);
}
// async global->LDS DMA, 16 B/lane; LDS dest = wave-uniform base + lane*16
__device__ __forceinline__ void gl_lds16(const u16* g, u16* l) {
  __builtin_amdgcn_global_load_lds(
      (const __attribute__((address_space(1))) unsigned int*)g,
      (__attribute__((address_space(3))) unsigned int*)l, 16, 0, 0);
}

// -------- fp32 -> bf16 elementwise cast (float4 vectorized) -------------
__global__ __launch_bounds__(256) void k_cast(const float* __restrict__ in,
                                              u16* __restrict__ out, int n4) {
  const int i = blockIdx.x * 256 + threadIdx.x;
  if (i >= n4) return;
  const float4 v = ((const float4*)in)[i];
  ushort4 o;
  o.x = f2bf(v.x); o.y = f2bf(v.y); o.z = f2bf(v.z); o.w = f2bf(v.w);
  ((ushort4*)out)[i] = o;
}

// -------- fp32 [R][C] -> bf16 out[C][R] transpose+cast ------------------
__global__ __launch_bounds__(256) void k_transpose_cast(const float* __restrict__ in,
                                                        u16* __restrict__ out,
                                                        int R, int C) {
  __shared__ __attribute__((aligned(16))) u16 tile[32][33];
  const int c0 = blockIdx.x * 32, r0 = blockIdx.y * 32;
  const int tx = threadIdx.x, ty = threadIdx.y;
#pragma unroll
  for (int i = 0; i < 4; ++i)
    tile[ty + 8 * i][tx] = f2bf(in[(r0 + ty + 8 * i) * C + c0 + tx]);
  __syncthreads();
#pragma unroll
  for (int i = 0; i < 4; ++i)
    out[(c0 + ty + 8 * i) * R + r0 + tx] = tile[tx][ty + 8 * i];
}

// ---------------- V -> V^T per (b,h): vt[bh][d][s] = qkv_v[b,s,h,d] ------
__global__ __launch_bounds__(256) void k_vtrans(const u16* __restrict__ qkv,
                                                u16* __restrict__ vt) {
  __shared__ __attribute__((aligned(16))) u16 tile[32][33];
  const int bh = blockIdx.z, b = bh >> 4, h = bh & 15;
  const int s0 = blockIdx.x * 32, d0 = blockIdx.y * 32;
  const int tx = threadIdx.x, ty = threadIdx.y;
#pragma unroll
  for (int i = 0; i < 4; ++i) {
    const int s = s0 + ty + 8 * i;
    tile[ty + 8 * i][tx] = qkv[(b * 2048 + s) * 6144 + 4096 + h * 128 + d0 + tx];
  }
  __syncthreads();
#pragma unroll
  for (int i = 0; i < 4; ++i) {
    const int d = d0 + ty + 8 * i;
    vt[bh * 262144 + d * 2048 + s0 + tx] = tile[tx][ty + 8 * i];
  }
}

// ---------------- RoPE in-place on Q and K sections of qkv (bf16) -------
__global__ __launch_bounds__(256) void k_rope(u16* __restrict__ qkv) {
  const int id = blockIdx.x * 256 + threadIdx.x;  // 8,388,608 threads
  const int j = id & 63;
  const int h = (id >> 6) & 15;
  const int sec = (id >> 10) & 1;
  const int m = id >> 11;  // b*2048+s
  const int s = m & 2047;
  const int base = m * 6144 + sec * 2048 + h * 128 + j;
  const float q0 = bf2f(qkv[base]);
  const float q1 = bf2f(qkv[base + 64]);
  const float inv = exp2f((float)j * -0.20762050593046014f);  // 10000^(-j/64)
  const float ang = (float)s * inv;
  float c, sn;
  sincosf(ang, &sn, &c);  // sincosf(x, SIN*, COS*) — sin FIRST
  qkv[base]      = f2bf(q0 * c - q1 * sn);
  qkv[base + 64] = f2bf(q1 * c + q0 * sn);
}

// ------- GEMM (m97 structure): C[M][N] = A[M][K] * BT[N][K]^T -----------
// kept for the fp32-A fallback path.
template <bool A_F32, typename OUT_T>
__global__ __launch_bounds__(256) void k_gemm_lds(const void* __restrict__ Ap, int lda,
                                                  const u16* __restrict__ BT,
                                                  OUT_T* __restrict__ C, int ldc,
                                                  int K) {
  __shared__ __attribute__((aligned(16))) u16 As[128 * 32];
  __shared__ __attribute__((aligned(16))) u16 Bs[128 * 32];
  const int tid = threadIdx.x;
  const int lane = tid & 63, wave = tid >> 6;
  const int lm = lane & 15, quad = lane >> 4;
  const int wm = wave >> 1, wn = wave & 1;
  const int m0 = blockIdx.y * 128, n0 = blockIdx.x * 128;
  const int srow = lane >> 2, scol = (lane & 3) * 8;  // staging map

  const f32x4 fzero = {0.f, 0.f, 0.f, 0.f};
  f32x4 acc[4][4];
#pragma unroll
  for (int i = 0; i < 4; ++i)
#pragma unroll
    for (int j = 0; j < 4; ++j) acc[i][j] = fzero;

  for (int k0 = 0; k0 < K; k0 += 32) {
    __syncthreads();
    if constexpr (A_F32) {
      const float* Af = (const float*)Ap;
#pragma unroll
      for (int i = 0; i < 2; ++i) {
        const int seg = tid + 256 * i;
        const int row = seg >> 2, c8 = (seg & 3) * 8;
        const float4 u = *(const float4*)&Af[(m0 + row) * lda + k0 + c8];
        const float4 w = *(const float4*)&Af[(m0 + row) * lda + k0 + c8 + 4];
        uint4 pk;
        pk.x = (unsigned)f2bf(u.x) | ((unsigned)f2bf(u.y) << 16);
        pk.y = (unsigned)f2bf(u.z) | ((unsigned)f2bf(u.w) << 16);
        pk.z = (unsigned)f2bf(w.x) | ((unsigned)f2bf(w.y) << 16);
        pk.w = (unsigned)f2bf(w.z) | ((unsigned)f2bf(w.w) << 16);
        *(uint4*)&As[row * 32 + c8] = pk;
      }
#pragma unroll
      for (int j = 0; j < 2; ++j) {
        const int rb = wave * 32 + j * 16;
        gl_lds16(&BT[(n0 + rb + srow) * K + k0 + scol], &Bs[rb * 32]);
      }
    } else {
      const u16* Ab = (const u16*)Ap;
#pragma unroll
      for (int j = 0; j < 2; ++j) {
        const int rb = wave * 32 + j * 16;
        gl_lds16(&Ab[(m0 + rb + srow) * lda + k0 + scol], &As[rb * 32]);
        gl_lds16(&BT[(n0 + rb + srow) * K + k0 + scol], &Bs[rb * 32]);
      }
    }
    __syncthreads();  // drains vmcnt (DMA) + lgkmcnt before reads

    s16x8 af[4], bfr[4];
#pragma unroll
    for (int t = 0; t < 4; ++t) {
      af[t]  = *(const s16x8*)&As[(wm * 64 + t * 16 + lm) * 32 + quad * 8];
      bfr[t] = *(const s16x8*)&Bs[(wn * 64 + t * 16 + lm) * 32 + quad * 8];
    }
#pragma unroll
    for (int mt = 0; mt < 4; ++mt)
#pragma unroll
      for (int nt = 0; nt < 4; ++nt)
        acc[mt][nt] = mfma16(af[mt], bfr[nt], acc[mt][nt]);
  }
#pragma unroll
  for (int mt = 0; mt < 4; ++mt)
#pragma unroll
    for (int nt = 0; nt < 4; ++nt)
#pragma unroll
      for (int r = 0; r < 4; ++r) {
        const float v = acc[mt][nt][r];
        const int idx = (m0 + wm * 64 + mt * 16 + quad * 4 + r) * ldc +
                        n0 + wn * 64 + nt * 16 + lm;
        if constexpr (sizeof(OUT_T) == 2) C[idx] = f2bf(v);
        else                              C[idx] = v;
      }
}

// ------- 256x128 GEMM v4: 3-deep rotating pipeline, zero grid tail ------
// C[M][N] = A[M][K] * BT[N][K]^T, bf16 in, OUT_T out. K=2048 = 32 tiles of
// BK=64 (2 K-half phases each). 8 waves as 4M x 2N, wave tile 64x64 (the
// harness-verified k_gemm_lds fragment/C mapping). Grid: M/256 x N/128 —
// QKV: 16x48=768 = exactly 3 full CU rounds; W_o: 16x16=256 = 1 round.
// LDS 144 KiB: 3 rotating tile buffers x 2 k-halves (A 16 KB + B 8 KB per
// half). 64-B rows: DMA writes and b128 fragment reads are contiguous
// 1024-B wave blocks -> bank-uniform, no swizzle needed.
// Phase (c,p): 8 ds_read_b128 -> stage half p of tile c+2 (3 gl_lds:
// 1B+2A, uniform per wave) -> vmcnt(9) -> s_barrier -> 16 MFMA (setprio).
// Ledger (3 loads/group, groups = phase-issues): steady outstanding after
// wait = 3 groups = 9; vmcnt(9) at (c,p)-mid certifies the half read at
// (c,p+1) — issue->certify distance 4 phases (~1000 cy > LLC latency,
// m201's depth-3 formula N = 3 loads x 3 groups). Drain: vmcnt(6)/(3)/(0)
// at (30,p0)/(30,p1)/(31,p0); no wait at (31,p1). WAR: stage(c+2) targets
// buffer (c+2)%3 = (c-1)%3, whose last reads completed >=2 barriers ago.
template <typename OUT_T>
__global__ __launch_bounds__(512, 2) void k_gemm256(const u16* __restrict__ A, int lda,
                                                    const u16* __restrict__ BT, int ldb,
                                                    OUT_T* __restrict__ C, int ldc) {
  __shared__ __attribute__((aligned(16))) u16 As[3][2][256 * 32];  // 96 KB
  __shared__ __attribute__((aligned(16))) u16 Bs[3][2][128 * 32];  // 48 KB
  const int tid = threadIdx.x;
  const int lane = tid & 63, wave = tid >> 6;
  const int lm = lane & 15, quad = lane >> 4;
  const int wm = wave >> 1, wn = wave & 1;  // 4M x 2N wave grid

  // XCD-aware swizzle (gridDim %8==0 for both grids -> bijective);
  // column-major tile map: consecutive swizzled ids share the B panel.
  int bid = (blockIdx.x & 7) * (gridDim.x >> 3) + (blockIdx.x >> 3);
  const int m0 = (bid & 15) * 256;  // M=4096 -> 16 tiles
  const int n0 = (bid >> 4) * 128;

  // stage k-half h of K-tile t into rotating buffer t%3 (3 gl_lds/wave)
  const int srow = lane >> 2, schunk = (lane & 3) * 8;
  auto stage_h = [&](int t, int h) {
    const int bi = t % 3;
    const int k0 = t * 64 + h * 32 + schunk;
    gl_lds16(&BT[(n0 + wave * 16 + srow) * ldb + k0],
             &Bs[bi][h][(wave * 16) * 32]);
    gl_lds16(&A[(m0 + wave * 32 + srow) * lda + k0],
             &As[bi][h][(wave * 32) * 32]);
    gl_lds16(&A[(m0 + wave * 32 + 16 + srow) * lda + k0],
             &As[bi][h][(wave * 32 + 16) * 32]);
  };

  const f32x4 fzero = {0.f, 0.f, 0.f, 0.f};
  f32x4 acc[4][4];
#pragma unroll
  for (int i = 0; i < 4; ++i)
#pragma unroll
    for (int j = 0; j < 4; ++j) acc[i][j] = fzero;

  // prologue: 4 groups in flight (tiles 0,1 both halves); certify h0(0)
  stage_h(0, 0); stage_h(0, 1); stage_h(1, 0); stage_h(1, 1);
  asm volatile("s_waitcnt vmcnt(9)" ::: "memory");
  asm volatile("s_barrier" ::: "memory");

  for (int c = 0; c < 32; ++c) {
    const int bi = c % 3;
#pragma unroll
    for (int p = 0; p < 2; ++p) {
      // ---- fragment reads (certified at previous phase's mid-wait)
      s16x8 bfr[4], afr[4];
#pragma unroll
      for (int nt = 0; nt < 4; ++nt)
        bfr[nt] = *(const s16x8*)
            &Bs[bi][p][(wn * 64 + nt * 16 + lm) * 32 + quad * 8];
#pragma unroll
      for (int i = 0; i < 4; ++i)
        afr[i] = *(const s16x8*)
            &As[bi][p][(wm * 64 + i * 16 + lm) * 32 + quad * 8];
      // ---- prefetch issue: half p of tile c+2
      if (c < 30) stage_h(c + 2, p);
      // ---- counted certification of next phase's half (drain at tail)
      if (c < 30) {
        asm volatile("s_waitcnt vmcnt(9)" ::: "memory");
      } else if (c == 30) {
        if (p == 0) asm volatile("s_waitcnt vmcnt(6)" ::: "memory");
        else        asm volatile("s_waitcnt vmcnt(3)" ::: "memory");
      } else {
        if (p == 0) asm volatile("s_waitcnt vmcnt(0)" ::: "memory");
      }
      asm volatile("s_barrier" ::: "memory");
      // ---- pure-MFMA cluster (compiler inserts lgkmcnt for afr/bfr deps)
      __builtin_amdgcn_s_setprio(1);
#pragma unroll
      for (int i = 0; i < 4; ++i)
#pragma unroll
        for (int nt = 0; nt < 4; ++nt)
          acc[i][nt] = mfma16(afr[i], bfr[nt], acc[i][nt]);
      __builtin_amdgcn_s_setprio(0);
      if (!(c == 31 && p == 1)) asm volatile("s_barrier" ::: "memory");
    }
  }

  // epilogue: C write (fragment->C mapping harness-verified)
#pragma unroll
  for (int i = 0; i < 4; ++i)
#pragma unroll
    for (int nt = 0; nt < 4; ++nt)
#pragma unroll
      for (int r = 0; r < 4; ++r) {
        const float v = acc[i][nt][r];
        const int idx = (m0 + wm * 64 + i * 16 + quad * 4 + r) * ldc +
                        n0 + wn * 64 + nt * 16 + lm;
        if constexpr (sizeof(OUT_T) == 2) C[idx] = f2bf(v);
        else                              C[idx] = v;
      }
}

// ---------------- causal flash attention, v4 ----------------------------
// 64-key tiles, causal pairing {pair, 31-pair} (33 uniform iters/block),
// DMA double-buffered K/V staging via global_load_lds (no VGPR round-trip,
// no spill), 1 barrier/iter. Unpadded LDS tiles use a global-side XOR
// swizzle (chunk cc = p ^ (row&7)) so b128 reads are bank-conflict-free.
__global__ __launch_bounds__(256) void k_attn(u16* __restrict__ qkv,
                                              const u16* __restrict__ vt) {
  __shared__ __attribute__((aligned(16))) u16 Ks[2][64 * 128];  // 2x16 KB, swizzled
  __shared__ __attribute__((aligned(16))) u16 Vs[2][128 * 64];  // 2x16 KB, swizzled
  __shared__ __attribute__((aligned(16))) u16 Ps[4 * 16 * 72];  //    9 KB
  const int bh = blockIdx.x, pair = blockIdx.y;
  const int b = bh >> 4, h = bh & 15;
  const int tid = threadIdx.x;
  const int lane = tid & 63, wave = tid >> 6;
  const int lm = lane & 15, quad = lane >> 4;
  const int pbase = wave * 1152;
  const int sw = lm & 7;  // read-side swizzle term
  const f32x4 fzero = {0.f, 0.f, 0.f, 0.f};

  const int phase_end = pair;  // it 0..pair: qtile=pair; it pair+1..32: qtile=31-pair

  // async-DMA K/V tile kt0 into buffer `buf` (global-side XOR swizzle)
  auto dma_tile = [&](int kt0, int buf) {
#pragma unroll
    for (int i = 0; i < 4; ++i) {  // K: [64 rows][128 u16], 16 rows/issue
      const int row = i * 16 + wave * 4 + (lane >> 4);
      const int cc = (lane & 15) ^ (row & 7);
      gl_lds16(&qkv[(b * 2048 + kt0 + row) * 6144 + 2048 + h * 128 + cc * 8],
               &Ks[buf][(i * 16 + wave * 4) * 128]);
    }
#pragma unroll
    for (int i = 0; i < 4; ++i) {  // V^T: [128 rows][64 u16], 32 rows/issue
      const int row = i * 32 + wave * 8 + (lane >> 3);
      const int cc = (lane & 7) ^ (row & 7);
      gl_lds16(&vt[bh * 262144 + row * 2048 + kt0 + cc * 8],
               &Vs[buf][(i * 32 + wave * 8) * 64]);
    }
  };

  // ---- prologue: stage tile for it=0 (kt=0) into buf 0 ----
  dma_tile(0, 0);

  // ---- phase-0 state (qtile = pair) ----
  int qtile = pair;
  int qb = qtile * 64;
  int qrow = qb + wave * 16 + lm;
  int qoff = (b * 2048 + qrow) * 6144 + h * 128;
  s16x8 qfrag[4];
#pragma unroll
  for (int c = 0; c < 4; ++c)
    qfrag[c] = *(const s16x8*)&qkv[qoff + c * 32 + quad * 8];
  f32x4 o[8];
#pragma unroll
  for (int dt = 0; dt < 8; ++dt) o[dt] = fzero;
  float m_run = NEG_BIG, l_run = 0.f;

  __syncthreads();  // buf0 DMA drained (vmcnt0 before barrier release)

  for (int it = 0; it < 33; ++it) {
    const int kt0 = (it <= phase_end ? it : it - phase_end - 1) * 64;
    const int buf = it & 1;

    // issue next tile's DMA into the other buffer (latency hidden by compute)
    if (it < 32) {
      const int nkt = (it + 1 <= phase_end ? it + 1 : it - phase_end) * 64;
      dma_tile(nkt, buf ^ 1);
    }

    // ---- S^T = K * Q^T on buf ----
    f32x4 sa[4];
#pragma unroll
    for (int ss = 0; ss < 4; ++ss) sa[ss] = fzero;
#pragma unroll
    for (int ss = 0; ss < 4; ++ss)
#pragma unroll
      for (int c = 0; c < 4; ++c) {
        const int ccs = (c * 4 + quad) ^ sw;
        s16x8 a = *(const s16x8*)&Ks[buf][(ss * 16 + lm) * 128 + ccs * 8];
        sa[ss] = mfma16(a, qfrag[c], sa[ss]);
      }

    // ---- scale + causal mask + online softmax (per column q = lm) ----
    float p[4][4];
    float vmax = NEG_BIG;
#pragma unroll
    for (int ss = 0; ss < 4; ++ss)
#pragma unroll
      for (int r = 0; r < 4; ++r) {
        const int kg = kt0 + ss * 16 + quad * 4 + r;
        float v = sa[ss][r] * ATTN_SCALE;
        if (kg > qrow) v = NEG_BIG;
        p[ss][r] = v;
        vmax = fmaxf(vmax, v);
      }
    vmax = fmaxf(vmax, __shfl_xor(vmax, 16, 64));
    vmax = fmaxf(vmax, __shfl_xor(vmax, 32, 64));
    const float m_new = fmaxf(m_run, vmax);
    const float alpha = __expf(m_run - m_new);
    float rsum = 0.f;
#pragma unroll
    for (int ss = 0; ss < 4; ++ss)
#pragma unroll
      for (int r = 0; r < 4; ++r) {
        p[ss][r] = __expf(p[ss][r] - m_new);  // masked: exp(-huge) = 0
        rsum += p[ss][r];
      }
    rsum += __shfl_xor(rsum, 16, 64);
    rsum += __shfl_xor(rsum, 32, 64);
    l_run = l_run * alpha + rsum;
    m_run = m_new;
#pragma unroll
    for (int dt = 0; dt < 8; ++dt) o[dt] *= alpha;

    // ---- P -> wave-private LDS bounce (intra-wave ordering, no barrier) --
#pragma unroll
    for (int ss = 0; ss < 4; ++ss)
#pragma unroll
      for (int r = 0; r < 4; ++r)
        Ps[pbase + lm * 72 + ss * 16 + quad * 4 + r] = f2bf(p[ss][r]);
    const s16x8 pv0 = *(const s16x8*)&Ps[pbase + lm * 72 + quad * 8];
    const s16x8 pv1 = *(const s16x8*)&Ps[pbase + lm * 72 + 32 + quad * 8];

    // ---- O^T += V^T * P^T over the two 32-key halves ----
#pragma unroll
    for (int dt = 0; dt < 8; ++dt) {
      const int c0 = (quad ^ sw) * 8, c1 = ((4 + quad) ^ sw) * 8;
      s16x8 a0 = *(const s16x8*)&Vs[buf][(dt * 16 + lm) * 64 + c0];
      s16x8 a1 = *(const s16x8*)&Vs[buf][(dt * 16 + lm) * 64 + c1];
      o[dt] = mfma16(a1, pv1, mfma16(a0, pv0, o[dt]));
    }

    // ---- phase boundary: write phase-0 output, reset for phase 1 ----
    if (it == phase_end) {
      const float inv_l = 1.0f / l_run;
#pragma unroll
      for (int dt = 0; dt < 8; ++dt)
#pragma unroll
        for (int r = 0; r < 4; ++r)
          qkv[qoff + dt * 16 + quad * 4 + r] = f2bf(o[dt][r] * inv_l);
      qtile = 31 - pair;
      qb = qtile * 64;
      qrow = qb + wave * 16 + lm;
      qoff = (b * 2048 + qrow) * 6144 + h * 128;
#pragma unroll
      for (int c = 0; c < 4; ++c)
        qfrag[c] = *(const s16x8*)&qkv[qoff + c * 32 + quad * 8];
#pragma unroll
      for (int dt = 0; dt < 8; ++dt) o[dt] = fzero;
      m_run = NEG_BIG; l_run = 0.f;
    }

    // single barrier: drains this iter's DMA (vmcnt0) + guards buf reuse
    if (it < 32) __syncthreads();
  }

  // ---- phase-1 epilogue ----
  const float inv_l = 1.0f / l_run;
#pragma unroll
  for (int dt = 0; dt < 8; ++dt)
#pragma unroll
    for (int r = 0; r < 4; ++r)
      qkv[qoff + dt * 16 + quad * 4 + r] = f2bf(o[dt][r] * inv_l);
}

// ---------------- host launcher ----------------------------------------
extern "C" void kernel_launch(void* const* d_in, const int* in_sizes, int n_in,
                              void* d_out, int out_size, void* d_ws, size_t ws_size,
                              hipStream_t stream) {
  const float* hidden = (const float*)d_in[0];  // [4096][2048] fp32
  const float* w_qkv  = (const float*)d_in[1];  // [2048][6144] fp32
  const float* w_o    = (const float*)d_in[2];  // [2048][2048] fp32
  float* out = (float*)d_out;                   // [4096][2048] fp32
  u16* ws = (u16*)d_ws;

  u16* qkv   = ws;
  u16* wqkvT = ws + 25165824;
  u16* vt    = ws + 25165824;
  u16* woT   = ws + 33554432;
  u16* hb    = ws + 37748736;
  const bool fast = ws_size >= (size_t)46137344 * 2;

  dim3 tb(32, 8);
  k_transpose_cast<<<dim3(192, 64), tb, 0, stream>>>(w_qkv, wqkvT, 2048, 6144);
  if (fast) {
    k_cast<<<8192, 256, 0, stream>>>(hidden, hb, 2097152);
    k_gemm256<u16><<<768, 512, 0, stream>>>(hb, 2048, wqkvT, 2048, qkv, 6144);
  } else {
    k_gemm_lds<true, u16><<<dim3(48, 32), 256, 0, stream>>>(hidden, 2048, wqkvT,
                                                            qkv, 6144, 2048);
  }
  k_rope<<<32768, 256, 0, stream>>>(qkv);
  k_vtrans<<<dim3(64, 4, 32), tb, 0, stream>>>(qkv, vt);
  k_transpose_cast<<<dim3(64, 64), tb, 0, stream>>>(w_o, woT, 2048, 2048);
  k_attn<<<dim3(32, 16), 256, 0, stream>>>(qkv, vt);  // x=bh (XCD locality)
  if (fast) {
    k_gemm256<float><<<256, 512, 0, stream>>>(qkv, 6144, woT, 2048, out, 2048);
  } else {
    k_gemm_lds<false, float><<<dim3(16, 32), 256, 0, stream>>>(qkv, 6144, woT,
                                                               out, 2048, 2048);
  }
}